// Round 2
// baseline (190.208 us; speedup 1.0000x reference)
//
#include <hip/hip_runtime.h>

#define BIGV 1e4f

constexpr int RH  = 8;   // output rows per wave
constexpr int TY  = 2;   // waves per block (stacked in y); block covers 16 rows
constexpr int PXL = 16;  // px per lane; wave covers 64*16 = 1024 px = full row

// Raw: 16 consecutive px per lane (4x float4). A wave spans the full image row,
// so the wave-edge x-halos are image borders -> compile-time BIGV, no edge loads.
struct Raw { float4 v[4]; };
// Row: 16 px + 2-px halos from neighbor lanes (BIGV at image border)
struct Row { float l0, l1; float m[PXL]; float r0, r1; };
// Ero: eroded cols -1..16 relative to lane base; e[p] = eroded col (p-1)
struct Ero { float e[PXL + 2]; };

__device__ __forceinline__ Raw load_raw(const float* __restrict__ img, int y,
                                        int lx, int H, int W) {
    Raw r;
    if (y >= 0 && y < H) {                       // wave-uniform (y uniform per wave)
        const float4* q = (const float4*)(img + (size_t)y * W + lx * PXL);
        r.v[0] = q[0]; r.v[1] = q[1]; r.v[2] = q[2]; r.v[3] = q[3];
    } else {
#pragma unroll
        for (int i = 0; i < 4; ++i) r.v[i] = make_float4(BIGV, BIGV, BIGV, BIGV);
    }
    return r;
}

__device__ __forceinline__ Row rowify(const Raw& r, int lx) {
    Row o;
#pragma unroll
    for (int i = 0; i < 4; ++i) {
        o.m[4*i+0] = r.v[i].x; o.m[4*i+1] = r.v[i].y;
        o.m[4*i+2] = r.v[i].z; o.m[4*i+3] = r.v[i].w;
    }
    float lz = __shfl_up(r.v[3].z, 1, 64);    // lane-1 px14 -> my col -2
    float lw = __shfl_up(r.v[3].w, 1, 64);    // lane-1 px15 -> my col -1
    float rx = __shfl_down(r.v[0].x, 1, 64);  // lane+1 px0  -> my col 16
    float ry = __shfl_down(r.v[0].y, 1, 64);  // lane+1 px1  -> my col 17
    o.l0 = (lx == 0)  ? BIGV : lz;
    o.l1 = (lx == 0)  ? BIGV : lw;
    o.r0 = (lx == 63) ? BIGV : rx;
    o.r1 = (lx == 63) ? BIGV : ry;
    return o;
}

// compile-time indexed access (q is constant under full unroll)
__device__ __forceinline__ float rget(const Row& r, int q) {
    if (q == -2)      return r.l0;
    if (q == -1)      return r.l1;
    if (q == PXL)     return r.r0;
    if (q == PXL + 1) return r.r1;
    return r.m[q];
}

// erosion of row r (rows a=r-1, b=r, c=r+1). CROSS folds the mask at compile time.
template <bool CROSS>
__device__ __forceinline__ Ero erode(const Row& a, const Row& b, const Row& c,
                                     const bool* m, int r, int H, int lx) {
    Ero e;
    if (r >= 0 && r < H) {                       // wave-uniform
#pragma unroll
        for (int p = 0; p < PXL + 2; ++p) {      // eroded col q = p-1
            float acc;
            if (CROSS) {
                acc = fminf(fminf(rget(a, p-1), rget(c, p-1)),
                            fminf(fminf(rget(b, p-2), rget(b, p)), rget(b, p-1)));
            } else {
                acc = BIGV;
#pragma unroll
                for (int k = 0; k < 9; ++k) {
                    const int di = k / 3, dj = k % 3;
                    const Row& rr = (di == 0) ? a : ((di == 1) ? b : c);
                    float t = rget(rr, p - 2 + dj);
                    acc = fminf(acc, m[k] ? t : BIGV);
                }
            }
            e.e[p] = acc;
        }
        if (lx == 0)  e.e[0]       = -BIGV;   // image col -1 is the dilation pad
        if (lx == 63) e.e[PXL + 1] = -BIGV;   // image col W  is the dilation pad
    } else {
#pragma unroll
        for (int p = 0; p < PXL + 2; ++p) e.e[p] = -BIGV;   // out-of-image eroded row
    }
    return e;
}

// dilation: output row y from eroded rows t=y-1, mi=y, bo=y+1
template <bool CROSS>
__device__ __forceinline__ void dilate(const Ero& t, const Ero& mi, const Ero& bo,
                                       const bool* m, float* o /*[16]*/) {
#pragma unroll
    for (int j = 0; j < PXL; ++j) {
        float acc;
        if (CROSS) {
            acc = fmaxf(fmaxf(t.e[j+1], bo.e[j+1]),
                        fmaxf(fmaxf(mi.e[j], mi.e[j+2]), mi.e[j+1]));
        } else {
            acc = -BIGV;
#pragma unroll
            for (int k = 0; k < 9; ++k) {
                const int di = k / 3, dj = k % 3;
                const Ero& ee = (di == 0) ? t : ((di == 1) ? mi : bo);
                acc = fmaxf(acc, m[k] ? ee.e[j + dj] : -BIGV);
            }
        }
        o[j] = acc;
    }
}

template <bool CROSS>
__device__ __forceinline__ void run(const float* __restrict__ img,
                                    float* __restrict__ out, const bool* m,
                                    int y0, int lx, int H, int W) {
    // prologue: rows y0-2 .. y0+2, erosions of rows y0-1, y0
    Raw rb = load_raw(img, y0 - 2, lx, H, W);
    Raw rc = load_raw(img, y0 - 1, lx, H, W);
    Raw rd = load_raw(img, y0,     lx, H, W);
    Raw re = load_raw(img, y0 + 1, lx, H, W);
    Raw p  = load_raw(img, y0 + 2, lx, H, W);   // consumed at i=0

    Row B   = rowify(rb, lx);
    Row C   = rowify(rc, lx);
    Row Cur = rowify(rd, lx);
    Ero E0 = erode<CROSS>(B, C, Cur, m, y0 - 1, H, lx);
    Row Nxt = rowify(re, lx);
    Ero E1 = erode<CROSS>(C, Cur, Nxt, m, y0, H, lx);

#pragma unroll
    for (int i = 0; i < RH; ++i) {
        const int y = y0 + i;
        Raw pn = p;
        if (i < RH - 1)                          // compile-time under unroll
            pn = load_raw(img, y + 3, lx, H, W); // next iter's row, in flight now
        Row N = rowify(p, lx);                   // Row(y+2)
        Ero E2 = erode<CROSS>(Cur, Nxt, N, m, y + 1, H, lx);
        float o[PXL];
        dilate<CROSS>(E0, E1, E2, m, o);
        float4* qo = (float4*)(out + (size_t)y * W + lx * PXL);
#pragma unroll
        for (int t4 = 0; t4 < 4; ++t4)
            qo[t4] = make_float4(o[4*t4], o[4*t4+1], o[4*t4+2], o[4*t4+3]);
        Cur = Nxt; Nxt = N;
        E0 = E1; E1 = E2;
        p = pn;
    }
}

__global__ __launch_bounds__(128, 3) void opening_kernel(
    const float* __restrict__ img, const int* __restrict__ kern,
    float* __restrict__ out, int H, int W)
{
    const int lx = threadIdx.x & 63;             // lane -> 16-px strip of the row
    const int ty = threadIdx.x >> 6;             // wave -> y group (wave-uniform)
    const int y0 = (blockIdx.x * TY + ty) * RH;
    const size_t pbase = (size_t)blockIdx.y * H * W;

    bool m[9];
#pragma unroll
    for (int k = 0; k < 9; ++k) m[k] = (kern[k] == 1);

    const bool cross = m[1] && m[3] && m[4] && m[5] && m[7] &&
                       !m[0] && !m[2] && !m[6] && !m[8];

    if (cross) run<true >(img + pbase, out + pbase, m, y0, lx, H, W);
    else       run<false>(img + pbase, out + pbase, m, y0, lx, H, W);
}

extern "C" void kernel_launch(void* const* d_in, const int* in_sizes, int n_in,
                              void* d_out, int out_size, void* d_ws, size_t ws_size,
                              hipStream_t stream) {
    const float* img  = (const float*)d_in[0];
    const int*   kern = (const int*)d_in[1];
    float*       out  = (float*)d_out;

    const int H = 1024, W = 1024;
    const int planes = in_sizes[0] / (H * W);    // B*C = 24

    dim3 block(128);
    dim3 grid(H / (TY * RH), planes);            // (64, 24) = 1536 blocks = 6/CU exact
    opening_kernel<<<grid, block, 0, stream>>>(img, kern, out, H, W);
}

// Round 3
// 184.555 us; speedup vs baseline: 1.0306x; 1.0306x over previous
//
#include <hip/hip_runtime.h>
#include <stdint.h>

#define BIGV 1e4f

constexpr int RH    = 8;     // output rows per wave-strip
constexpr int NSLOT = 5;     // LDS ring slots (rows); 5*4KB = 20KB -> 8 blocks/CU
constexpr int WROW  = 1024;  // floats per image row (W)

struct Row { float2 L; float4 M; float2 R; };   // cols gx-2 .. gx+5
struct Ero { float eL; float4 eM; float eR; };  // eroded cols gx-1 .. gx+4

#define WAITVM(n)  asm volatile("s_waitcnt vmcnt(" #n ")" ::: "memory")
#define WAITALL0() asm volatile("s_waitcnt vmcnt(0) lgkmcnt(0)" ::: "memory")
#define WAITLG0()  asm volatile("s_waitcnt lgkmcnt(0)" ::: "memory")
#define SCHED0()   __builtin_amdgcn_sched_barrier(0)

__device__ __forceinline__ float min3f(float a, float b, float c) { return fminf(fminf(a, b), c); }
__device__ __forceinline__ float max3f(float a, float b, float c) { return fmaxf(fmaxf(a, b), c); }

// async global->LDS DMA, 16B per lane; dest = wave-uniform base + lane*16 (HW rule)
__device__ __forceinline__ void gld16(const void* g, void* l) {
    __builtin_amdgcn_global_load_lds(
        (const __attribute__((address_space(1))) void*)g,
        (__attribute__((address_space(3))) void*)l, 16, 0, 0);
}

// stage image row r (clamped; OOB rows overridden at consume) into ring slot.
// 4 chunks of 1KB; lane lx supplies floats [4lx..4lx+3] of each 256-px chunk.
__device__ __forceinline__ void dma_row(const float* __restrict__ img, float* lds,
                                        int slot, int r, int H, int W, int lx) {
    const int rc = min(max(r, 0), H - 1);
    const float* src = img + (size_t)rc * W + 4 * lx;   // per-lane global src
    float* dst = lds + slot * WROW;                     // wave-uniform LDS base
#pragma unroll
    for (int c = 0; c < 4; ++c)
        gld16(src + c * 256, dst + c * 256);            // 4 vmem ops per row
}

// read raw row r from its ring slot into 4 strip-Rows (halos direct from LDS).
// per strip: 1x ds_read_b128 (contiguous across lanes -> conflict-free) + 2x b64.
__device__ __forceinline__ void read_row4(const float* lds, int slot, int lx,
                                          int r, int H, Row* w) {
    if (r >= 0 && r < H) {                              // wave-uniform
        const float* sb = lds + slot * WROW;
#pragma unroll
        for (int c = 0; c < 4; ++c) {
            const int fb = c * 256 + 4 * lx;
            w[c].M = *(const float4*)(sb + fb);
            if (c == 0 && lx == 0) w[c].L = make_float2(BIGV, BIGV);   // image x edge
            else                   w[c].L = *(const float2*)(sb + fb - 2);
            if (c == 3 && lx == 63) w[c].R = make_float2(BIGV, BIGV);  // image x edge
            else                    w[c].R = *(const float2*)(sb + fb + 4);
        }
    } else {
#pragma unroll
        for (int c = 0; c < 4; ++c) {
            w[c].L = make_float2(BIGV, BIGV);
            w[c].M = make_float4(BIGV, BIGV, BIGV, BIGV);
            w[c].R = make_float2(BIGV, BIGV);
        }
    }
}

// compile-time indexed access (folds under full unroll) — generic path only
__device__ __forceinline__ float rget(const Row& r, int q) {
    switch (q) {
        case -2: return r.L.x; case -1: return r.L.y;
        case 0:  return r.M.x; case 1:  return r.M.y;
        case 2:  return r.M.z; case 3:  return r.M.w;
        case 4:  return r.R.x; default: return r.R.y;
    }
}
__device__ __forceinline__ float eget(const Ero& e, int q) {
    switch (q) {
        case -1: return e.eL;
        case 0:  return e.eM.x; case 1:  return e.eM.y;
        case 2:  return e.eM.z; case 3:  return e.eM.w;
        default: return e.eR;
    }
}

// ---- cross structuring element fast path: min over {C,N,S,W,E} ----
__device__ __forceinline__ Ero erode_cross(const Row& a, const Row& b, const Row& c,
                                           int r, int H, int gx, int W) {
    Ero e;
    if (r >= 0 && r < H) {                         // wave-uniform
        e.eL   = min3f(min3f(a.L.y, b.L.y, c.L.y), b.L.x, b.M.x);
        e.eM.x = min3f(min3f(a.M.x, b.M.x, c.M.x), b.L.y, b.M.y);
        e.eM.y = min3f(min3f(a.M.y, b.M.y, c.M.y), b.M.x, b.M.z);
        e.eM.z = min3f(min3f(a.M.z, b.M.z, c.M.z), b.M.y, b.M.w);
        e.eM.w = min3f(min3f(a.M.w, b.M.w, c.M.w), b.M.z, b.R.x);
        e.eR   = min3f(min3f(a.R.x, b.R.x, c.R.x), b.M.w, b.R.y);
        if (gx == 0)     e.eL = -BIGV;   // eroded col -1 is the dilation pad
        if (gx + 4 >= W) e.eR = -BIGV;   // eroded col W  is the dilation pad
    } else {
        e.eL = -BIGV; e.eM = make_float4(-BIGV, -BIGV, -BIGV, -BIGV); e.eR = -BIGV;
    }
    return e;
}

__device__ __forceinline__ float4 dilate_cross(const Ero& t, const Ero& m, const Ero& b) {
    float4 o;
    o.x = max3f(max3f(t.eM.x, m.eM.x, b.eM.x), m.eL,   m.eM.y);
    o.y = max3f(max3f(t.eM.y, m.eM.y, b.eM.y), m.eM.x, m.eM.z);
    o.z = max3f(max3f(t.eM.z, m.eM.z, b.eM.z), m.eM.y, m.eM.w);
    o.w = max3f(max3f(t.eM.w, m.eM.w, b.eM.w), m.eM.z, m.eR);
    return o;
}

// ---- generic runtime-mask fallback (uniform branch; not taken in this bench) ----
__device__ __forceinline__ Ero erode_gen(const Row& a, const Row& b, const Row& c,
                                         const bool* m, int r, int H, int gx, int W) {
    Ero e;
    if (r >= 0 && r < H) {
        float v[6];
#pragma unroll
        for (int p = 0; p < 6; ++p) {              // eroded column gx-1+p
            float acc = BIGV;
#pragma unroll
            for (int k = 0; k < 9; ++k) {
                const int di = k / 3, dj = k % 3;
                const Row& rr = (di == 0) ? a : ((di == 1) ? b : c);
                float t = rget(rr, p - 2 + dj);
                acc = fminf(acc, m[k] ? t : BIGV);
            }
            v[p] = acc;
        }
        e.eL = v[0]; e.eM.x = v[1]; e.eM.y = v[2]; e.eM.z = v[3]; e.eM.w = v[4]; e.eR = v[5];
        if (gx == 0)     e.eL = -BIGV;
        if (gx + 4 >= W) e.eR = -BIGV;
    } else {
        e.eL = -BIGV; e.eM = make_float4(-BIGV, -BIGV, -BIGV, -BIGV); e.eR = -BIGV;
    }
    return e;
}

__device__ __forceinline__ float4 dilate_gen(const Ero& e0, const Ero& e1, const Ero& e2,
                                             const bool* m) {
    float o[4];
#pragma unroll
    for (int j = 0; j < 4; ++j) {
        float acc = -BIGV;
#pragma unroll
        for (int k = 0; k < 9; ++k) {
            const int di = k / 3, dj = k % 3;
            const Ero& ee = (di == 0) ? e0 : ((di == 1) ? e1 : e2);
            acc = fmaxf(acc, m[k] ? eget(ee, j + dj - 1) : -BIGV);
        }
        o[j] = acc;
    }
    return make_float4(o[0], o[1], o[2], o[3]);
}

template <bool CROSS>
__device__ __forceinline__ void run(const float* __restrict__ img, float* __restrict__ out,
                                    float* lds, const bool* m, int y0, int lx, int H, int W) {
    WAITALL0();                                 // clean vmcnt baseline (kern loads etc.)
    // ---- prologue: stage rows y0-2..y0+2 into slots 0..4 (20 vmem ops) ----
#pragma unroll
    for (int k = 0; k < NSLOT; ++k) dma_row(img, lds, k, y0 - 2 + k, H, W, lx);
    SCHED0();
    WAITVM(4);                                  // rows y0-2..y0+1 landed (y0+2 in flight)
    SCHED0();
    Row B[4], C[4], Cur[4], Nxt[4];
    read_row4(lds, 0, lx, y0 - 2, H, B);
    read_row4(lds, 1, lx, y0 - 1, H, C);
    read_row4(lds, 2, lx, y0,     H, Cur);
    read_row4(lds, 3, lx, y0 + 1, H, Nxt);
    WAITLG0();                                  // reads drained before slot reuse
    SCHED0();
    dma_row(img, lds, 0, y0 + 3, H, W, lx);     // refill consumed slots (12 ops)
    dma_row(img, lds, 1, y0 + 4, H, W, lx);
    dma_row(img, lds, 2, y0 + 5, H, W, lx);
    SCHED0();
    Ero E0[4], E1[4];
#pragma unroll
    for (int c = 0; c < 4; ++c) {
        const int gx = c * 256 + 4 * lx;
        E0[c] = CROSS ? erode_cross(B[c], C[c], Cur[c], y0 - 1, H, gx, W)
                      : erode_gen (B[c], C[c], Cur[c], m, y0 - 1, H, gx, W);
        E1[c] = CROSS ? erode_cross(C[c], Cur[c], Nxt[c], y0, H, gx, W)
                      : erode_gen (C[c], Cur[c], Nxt[c], m, y0, H, gx, W);
    }

    // ---- steady state: per iter {wait K_i, ds_read row y+2, compute, store, DMA y+6} ----
    // K_i derived from FIFO issue order (4 DMA/row, 4 stores/iter), order pinned by SCHED0.
#pragma unroll
    for (int i = 0; i < RH; ++i) {
        const int y = y0 + i;
        if      (i == 0) WAITVM(12);
        else if (i == 1) WAITVM(16);
        else if (i == 2) WAITVM(20);
        else if (i == 3) WAITVM(24);
        else if (i == 4) WAITVM(24);
        else if (i == 5) WAITVM(20);
        else if (i == 6) WAITVM(16);
        else             WAITVM(12);
        SCHED0();
        Row N[4];
        read_row4(lds, (i + 4) % NSLOT, lx, y + 2, H, N);
#pragma unroll
        for (int c = 0; c < 4; ++c) {
            const int gx = c * 256 + 4 * lx;
            Ero E2 = CROSS ? erode_cross(Cur[c], Nxt[c], N[c], y + 1, H, gx, W)
                           : erode_gen (Cur[c], Nxt[c], N[c], m, y + 1, H, gx, W);
            float4 o = CROSS ? dilate_cross(E0[c], E1[c], E2)
                             : dilate_gen (E0[c], E1[c], E2, m);
            *(float4*)(out + (size_t)y * W + gx) = o;
            E0[c] = E1[c]; E1[c] = E2;
            Cur[c] = Nxt[c]; Nxt[c] = N[c];
        }
        SCHED0();                               // stores issue before next DMA group
        if (i < RH - 4) {                       // rows y0+6..y0+9 at i=0..3
            dma_row(img, lds, (i + 3) % NSLOT, y + 6, H, W, lx);
            SCHED0();
        }
    }
}

__global__ __launch_bounds__(64, 2) void opening_kernel(
    const float* __restrict__ img, const int* __restrict__ kern,
    float* __restrict__ out, int H, int W)
{
    __shared__ float lds[NSLOT * WROW];         // 20 KB -> 8 blocks/CU (160 KB exact)
    const int lx = threadIdx.x;                 // 0..63, one wave per block

    // XCD swizzle: XCD k owns a contiguous chunk (3 planes); plane = 4 MiB = one L2
    const int bid   = blockIdx.x;
    const int chunk = gridDim.x >> 3;           // gridDim.x is a multiple of 8
    const int swz   = (bid & 7) * chunk + (bid >> 3);
    const int sy    = swz & 127;                // strip within plane (H/RH = 128)
    const int plane = swz >> 7;
    const int y0    = sy * RH;
    const size_t pbase = (size_t)plane * H * W;

    bool m[9];
#pragma unroll
    for (int k = 0; k < 9; ++k) m[k] = (kern[k] == 1);
    const bool cross = m[1] && m[3] && m[4] && m[5] && m[7] &&
                       !m[0] && !m[2] && !m[6] && !m[8];

    if (cross) run<true >(img + pbase, out + pbase, lds, m, y0, lx, H, W);
    else       run<false>(img + pbase, out + pbase, lds, m, y0, lx, H, W);
}

extern "C" void kernel_launch(void* const* d_in, const int* in_sizes, int n_in,
                              void* d_out, int out_size, void* d_ws, size_t ws_size,
                              hipStream_t stream) {
    const float* img  = (const float*)d_in[0];
    const int*   kern = (const int*)d_in[1];
    float*       out  = (float*)d_out;

    const int H = 1024, W = 1024;
    const int planes = in_sizes[0] / (H * W);   // B*C = 24

    dim3 block(64);                             // 1 wave per block
    dim3 grid((H / RH) * planes);               // 128 * 24 = 3072 blocks
    opening_kernel<<<grid, block, 0, stream>>>(img, kern, out, H, W);
}

// Round 5
// 179.174 us; speedup vs baseline: 1.0616x; 1.0300x over previous
//
#include <hip/hip_runtime.h>

#define BIGV 1e4f

constexpr int RH = 8;   // output rows per thread
constexpr int TY = 4;   // waves per block (each wave = one y-group); block covers 32 rows

typedef float f32x4 __attribute__((ext_vector_type(4)));   // native vec for nt-store

struct Raw { float4 M; float2 L; float2 R; };   // M: gx..gx+3 ; L/R only valid on edge lanes
struct Row { float2 L; float4 M; float2 R; };   // img columns gx-2 .. gx+5
struct Ero { float eL; float4 eM; float eR; };  // eroded columns gx-1 .. gx+4

__device__ __forceinline__ float min3f(float a, float b, float c) { return fminf(fminf(a, b), c); }
__device__ __forceinline__ float max3f(float a, float b, float c) { return fmaxf(fmaxf(a, b), c); }

// raw load: one float4 per lane; halo float2 only on the wave's edge lanes (exec-masked)
__device__ __forceinline__ Raw load_raw(const float* __restrict__ img, int y, int gx,
                                        int lx, int H, int W) {
    Raw r;
    r.L = make_float2(BIGV, BIGV);
    r.R = make_float2(BIGV, BIGV);
    if (y >= 0 && y < H) {                         // wave-uniform (y uniform per wave)
        const float* q = img + (size_t)y * W;
        r.M = *(const float4*)(q + gx);
        if (lx == 0  && gx > 0)     r.L = *(const float2*)(q + gx - 2);
        if (lx == 63 && gx + 4 < W) r.R = *(const float2*)(q + gx + 4);
    } else {
        r.M = make_float4(BIGV, BIGV, BIGV, BIGV);
    }
    return r;
}

// build full 8-wide row: interior halo from neighbor lanes via shuffle
__device__ __forceinline__ Row rowify(const Raw& r, int lx) {
    Row o;
    o.M = r.M;
    float lz = __shfl_up(r.M.z, 1, 64);    // lane-1's gx+2  -> my gx-2
    float lw = __shfl_up(r.M.w, 1, 64);    // lane-1's gx+3  -> my gx-1
    float rx = __shfl_down(r.M.x, 1, 64);  // lane+1's gx    -> my gx+4
    float ry = __shfl_down(r.M.y, 1, 64);  // lane+1's gx+1  -> my gx+5
    o.L = (lx == 0)  ? r.L : make_float2(lz, lw);
    o.R = (lx == 63) ? r.R : make_float2(rx, ry);
    return o;
}

// compile-time indexed access (folds under full unroll) — generic path only
__device__ __forceinline__ float rget(const Row& r, int q) {
    switch (q) {
        case -2: return r.L.x; case -1: return r.L.y;
        case 0:  return r.M.x; case 1:  return r.M.y;
        case 2:  return r.M.z; case 3:  return r.M.w;
        case 4:  return r.R.x; default: return r.R.y;
    }
}
__device__ __forceinline__ float eget(const Ero& e, int q) {
    switch (q) {
        case -1: return e.eL;
        case 0:  return e.eM.x; case 1:  return e.eM.y;
        case 2:  return e.eM.z; case 3:  return e.eM.w;
        default: return e.eR;
    }
}

// ---- cross structuring element fast path: min over {C,N,S,W,E} ----
__device__ __forceinline__ Ero erode_cross(const Row& a, const Row& b, const Row& c,
                                           int r, int H, int gx, int W) {
    Ero e;
    if (r >= 0 && r < H) {                         // wave-uniform
        e.eL   = min3f(min3f(a.L.y, b.L.y, c.L.y), b.L.x, b.M.x);
        e.eM.x = min3f(min3f(a.M.x, b.M.x, c.M.x), b.L.y, b.M.y);
        e.eM.y = min3f(min3f(a.M.y, b.M.y, c.M.y), b.M.x, b.M.z);
        e.eM.z = min3f(min3f(a.M.z, b.M.z, c.M.z), b.M.y, b.M.w);
        e.eM.w = min3f(min3f(a.M.w, b.M.w, c.M.w), b.M.z, b.R.x);
        e.eR   = min3f(min3f(a.R.x, b.R.x, c.R.x), b.M.w, b.R.y);
        if (gx == 0)     e.eL = -BIGV;   // eroded col -1 is the dilation pad
        if (gx + 4 >= W) e.eR = -BIGV;   // eroded col W  is the dilation pad
    } else {
        e.eL = -BIGV; e.eM = make_float4(-BIGV, -BIGV, -BIGV, -BIGV); e.eR = -BIGV;
    }
    return e;
}

__device__ __forceinline__ float4 dilate_cross(const Ero& t, const Ero& m, const Ero& b) {
    float4 o;
    o.x = max3f(max3f(t.eM.x, m.eM.x, b.eM.x), m.eL,   m.eM.y);
    o.y = max3f(max3f(t.eM.y, m.eM.y, b.eM.y), m.eM.x, m.eM.z);
    o.z = max3f(max3f(t.eM.z, m.eM.z, b.eM.z), m.eM.y, m.eM.w);
    o.w = max3f(max3f(t.eM.w, m.eM.w, b.eM.w), m.eM.z, m.eR);
    return o;
}

// ---- generic runtime-mask fallback (uniform branch; not taken in this bench) ----
__device__ __forceinline__ Ero erode_gen(const Row& a, const Row& b, const Row& c,
                                         const bool* m, int r, int H, int gx, int W) {
    Ero e;
    if (r >= 0 && r < H) {
        float v[6];
#pragma unroll
        for (int p = 0; p < 6; ++p) {              // eroded column gx-1+p
            float acc = BIGV;
#pragma unroll
            for (int k = 0; k < 9; ++k) {
                const int di = k / 3, dj = k % 3;
                const Row& rr = (di == 0) ? a : ((di == 1) ? b : c);
                float t = rget(rr, p - 2 + dj);
                acc = fminf(acc, m[k] ? t : BIGV);
            }
            v[p] = acc;
        }
        e.eL = v[0]; e.eM.x = v[1]; e.eM.y = v[2]; e.eM.z = v[3]; e.eM.w = v[4]; e.eR = v[5];
        if (gx == 0)     e.eL = -BIGV;
        if (gx + 4 >= W) e.eR = -BIGV;
    } else {
        e.eL = -BIGV; e.eM = make_float4(-BIGV, -BIGV, -BIGV, -BIGV); e.eR = -BIGV;
    }
    return e;
}

__device__ __forceinline__ float4 dilate_gen(const Ero& e0, const Ero& e1, const Ero& e2,
                                             const bool* m) {
    float o[4];
#pragma unroll
    for (int j = 0; j < 4; ++j) {
        float acc = -BIGV;
#pragma unroll
        for (int k = 0; k < 9; ++k) {
            const int di = k / 3, dj = k % 3;
            const Ero& ee = (di == 0) ? e0 : ((di == 1) ? e1 : e2);
            float t = eget(ee, j + dj - 1);
            acc = fmaxf(acc, m[k] ? t : -BIGV);
        }
        o[j] = acc;
    }
    return make_float4(o[0], o[1], o[2], o[3]);
}

template <bool CROSS>
__device__ __forceinline__ void run(const float* __restrict__ img, float* __restrict__ out,
                                    const bool* m, int gx, int y0, int lx, int H, int W) {
    // prologue: Rows y0-2..y0+1, Eros y0-1, y0
    Raw rb = load_raw(img, y0 - 2, gx, lx, H, W);
    Raw rc = load_raw(img, y0 - 1, gx, lx, H, W);
    Raw rd = load_raw(img, y0,     gx, lx, H, W);
    Raw re = load_raw(img, y0 + 1, gx, lx, H, W);
    Raw pref = load_raw(img, y0 + 2, gx, lx, H, W);   // prefetch for i=0

    Row B   = rowify(rb, lx);
    Row C   = rowify(rc, lx);
    Row Cur = rowify(rd, lx);   // Row(y0)
    Ero E0 = CROSS ? erode_cross(B, C, Cur, y0 - 1, H, gx, W)
                   : erode_gen(B, C, Cur, m, y0 - 1, H, gx, W);
    Row Nxt = rowify(re, lx);   // Row(y0+1)
    Ero E1 = CROSS ? erode_cross(C, Cur, Nxt, y0, H, gx, W)
                   : erode_gen(C, Cur, Nxt, m, y0, H, gx, W);

#pragma unroll
    for (int i = 0; i < RH; ++i) {
        const int y = y0 + i;
        Raw pref2 = pref;
        if (i < RH - 1)                               // compile-time under unroll
            pref2 = load_raw(img, y + 3, gx, lx, H, W);  // prefetch next iter's row
        Row N = rowify(pref, lx);                     // Row(y+2), loaded last iter
        Ero E2 = CROSS ? erode_cross(Cur, Nxt, N, y + 1, H, gx, W)
                       : erode_gen(Cur, Nxt, N, m, y + 1, H, gx, W);
        float4 o = CROSS ? dilate_cross(E0, E1, E2) : dilate_gen(E0, E1, E2, m);
        // NON-TEMPORAL store (native clang vector type — the builtin rejects
        // HIP_vector_type): keep the 96 MiB write stream out of L2/LLC so the
        // input image stays LLC-resident (across dispatches and for halo re-reads).
        f32x4 ov; ov.x = o.x; ov.y = o.y; ov.z = o.z; ov.w = o.w;
        __builtin_nontemporal_store(ov, (f32x4*)(out + (size_t)y * W + gx));
        Cur = Nxt; Nxt = N;
        E0 = E1; E1 = E2;
        pref = pref2;
    }
}

__global__ __launch_bounds__(256) void opening_kernel(
    const float* __restrict__ img, const int* __restrict__ kern,
    float* __restrict__ out, int H, int W)
{
    const int lx = threadIdx.x & 63;          // lane -> x strip
    const int ty = threadIdx.x >> 6;          // wave -> y group (wave-uniform)
    const int gx = blockIdx.x * 256 + lx * 4;
    const int y0 = (blockIdx.y * TY + ty) * RH;
    const size_t pbase = (size_t)blockIdx.z * H * W;

    bool m[9];
#pragma unroll
    for (int k = 0; k < 9; ++k) m[k] = (kern[k] == 1);

    const bool cross = m[1] && m[3] && m[4] && m[5] && m[7] &&
                       !m[0] && !m[2] && !m[6] && !m[8];

    if (cross) run<true >(img + pbase, out + pbase, m, gx, y0, lx, H, W);
    else       run<false>(img + pbase, out + pbase, m, gx, y0, lx, H, W);
}

extern "C" void kernel_launch(void* const* d_in, const int* in_sizes, int n_in,
                              void* d_out, int out_size, void* d_ws, size_t ws_size,
                              hipStream_t stream) {
    const float* img  = (const float*)d_in[0];
    const int*   kern = (const int*)d_in[1];
    float*       out  = (float*)d_out;

    const int H = 1024, W = 1024;
    const int planes = in_sizes[0] / (H * W);   // B*C = 24

    dim3 block(256);
    dim3 grid(W / 256, H / (TY * RH), planes);  // (4, 32, 24) = 3072 blocks
    opening_kernel<<<grid, block, 0, stream>>>(img, kern, out, H, W);
}

// Round 6
// 179.017 us; speedup vs baseline: 1.0625x; 1.0009x over previous
//
#include <hip/hip_runtime.h>

#define BIGV 1e4f

constexpr int RH = 8;   // output rows per thread
constexpr int TY = 4;   // waves per block (each wave = one y-group); strip covers 32 rows

typedef float f32x4 __attribute__((ext_vector_type(4)));   // native vec for nt-store

struct Raw { float4 M; float2 L; float2 R; };   // M: gx..gx+3 ; L/R only valid on edge lanes
struct Row { float2 L; float4 M; float2 R; };   // img columns gx-2 .. gx+5
struct Ero { float eL; float4 eM; float eR; };  // eroded columns gx-1 .. gx+4

__device__ __forceinline__ float min3f(float a, float b, float c) { return fminf(fminf(a, b), c); }
__device__ __forceinline__ float max3f(float a, float b, float c) { return fmaxf(fmaxf(a, b), c); }

// raw load: one float4 per lane; halo float2 only on the wave's edge lanes (exec-masked)
__device__ __forceinline__ Raw load_raw(const float* __restrict__ img, int y, int gx,
                                        int lx, int H, int W) {
    Raw r;
    r.L = make_float2(BIGV, BIGV);
    r.R = make_float2(BIGV, BIGV);
    if (y >= 0 && y < H) {                         // wave-uniform (y uniform per wave)
        const float* q = img + (size_t)y * W;
        r.M = *(const float4*)(q + gx);
        if (lx == 0  && gx > 0)     r.L = *(const float2*)(q + gx - 2);
        if (lx == 63 && gx + 4 < W) r.R = *(const float2*)(q + gx + 4);
    } else {
        r.M = make_float4(BIGV, BIGV, BIGV, BIGV);
    }
    return r;
}

// build full 8-wide row: interior halo from neighbor lanes via shuffle
__device__ __forceinline__ Row rowify(const Raw& r, int lx) {
    Row o;
    o.M = r.M;
    float lz = __shfl_up(r.M.z, 1, 64);    // lane-1's gx+2  -> my gx-2
    float lw = __shfl_up(r.M.w, 1, 64);    // lane-1's gx+3  -> my gx-1
    float rx = __shfl_down(r.M.x, 1, 64);  // lane+1's gx    -> my gx+4
    float ry = __shfl_down(r.M.y, 1, 64);  // lane+1's gx+1  -> my gx+5
    o.L = (lx == 0)  ? r.L : make_float2(lz, lw);
    o.R = (lx == 63) ? r.R : make_float2(rx, ry);
    return o;
}

// compile-time indexed access (folds under full unroll) — generic path only
__device__ __forceinline__ float rget(const Row& r, int q) {
    switch (q) {
        case -2: return r.L.x; case -1: return r.L.y;
        case 0:  return r.M.x; case 1:  return r.M.y;
        case 2:  return r.M.z; case 3:  return r.M.w;
        case 4:  return r.R.x; default: return r.R.y;
    }
}
__device__ __forceinline__ float eget(const Ero& e, int q) {
    switch (q) {
        case -1: return e.eL;
        case 0:  return e.eM.x; case 1:  return e.eM.y;
        case 2:  return e.eM.z; case 3:  return e.eM.w;
        default: return e.eR;
    }
}

// ---- cross structuring element fast path: min over {C,N,S,W,E} ----
__device__ __forceinline__ Ero erode_cross(const Row& a, const Row& b, const Row& c,
                                           int r, int H, int gx, int W) {
    Ero e;
    if (r >= 0 && r < H) {                         // wave-uniform
        e.eL   = min3f(min3f(a.L.y, b.L.y, c.L.y), b.L.x, b.M.x);
        e.eM.x = min3f(min3f(a.M.x, b.M.x, c.M.x), b.L.y, b.M.y);
        e.eM.y = min3f(min3f(a.M.y, b.M.y, c.M.y), b.M.x, b.M.z);
        e.eM.z = min3f(min3f(a.M.z, b.M.z, c.M.z), b.M.y, b.M.w);
        e.eM.w = min3f(min3f(a.M.w, b.M.w, c.M.w), b.M.z, b.R.x);
        e.eR   = min3f(min3f(a.R.x, b.R.x, c.R.x), b.M.w, b.R.y);
        if (gx == 0)     e.eL = -BIGV;   // eroded col -1 is the dilation pad
        if (gx + 4 >= W) e.eR = -BIGV;   // eroded col W  is the dilation pad
    } else {
        e.eL = -BIGV; e.eM = make_float4(-BIGV, -BIGV, -BIGV, -BIGV); e.eR = -BIGV;
    }
    return e;
}

__device__ __forceinline__ float4 dilate_cross(const Ero& t, const Ero& m, const Ero& b) {
    float4 o;
    o.x = max3f(max3f(t.eM.x, m.eM.x, b.eM.x), m.eL,   m.eM.y);
    o.y = max3f(max3f(t.eM.y, m.eM.y, b.eM.y), m.eM.x, m.eM.z);
    o.z = max3f(max3f(t.eM.z, m.eM.z, b.eM.z), m.eM.y, m.eM.w);
    o.w = max3f(max3f(t.eM.w, m.eM.w, b.eM.w), m.eM.z, m.eR);
    return o;
}

// ---- generic runtime-mask fallback (uniform branch; not taken in this bench) ----
__device__ __forceinline__ Ero erode_gen(const Row& a, const Row& b, const Row& c,
                                         const bool* m, int r, int H, int gx, int W) {
    Ero e;
    if (r >= 0 && r < H) {
        float v[6];
#pragma unroll
        for (int p = 0; p < 6; ++p) {              // eroded column gx-1+p
            float acc = BIGV;
#pragma unroll
            for (int k = 0; k < 9; ++k) {
                const int di = k / 3, dj = k % 3;
                const Row& rr = (di == 0) ? a : ((di == 1) ? b : c);
                float t = rget(rr, p - 2 + dj);
                acc = fminf(acc, m[k] ? t : BIGV);
            }
            v[p] = acc;
        }
        e.eL = v[0]; e.eM.x = v[1]; e.eM.y = v[2]; e.eM.z = v[3]; e.eM.w = v[4]; e.eR = v[5];
        if (gx == 0)     e.eL = -BIGV;
        if (gx + 4 >= W) e.eR = -BIGV;
    } else {
        e.eL = -BIGV; e.eM = make_float4(-BIGV, -BIGV, -BIGV, -BIGV); e.eR = -BIGV;
    }
    return e;
}

__device__ __forceinline__ float4 dilate_gen(const Ero& e0, const Ero& e1, const Ero& e2,
                                             const bool* m) {
    float o[4];
#pragma unroll
    for (int j = 0; j < 4; ++j) {
        float acc = -BIGV;
#pragma unroll
        for (int k = 0; k < 9; ++k) {
            const int di = k / 3, dj = k % 3;
            const Ero& ee = (di == 0) ? e0 : ((di == 1) ? e1 : e2);
            float t = eget(ee, j + dj - 1);
            acc = fmaxf(acc, m[k] ? t : -BIGV);
        }
        o[j] = acc;
    }
    return make_float4(o[0], o[1], o[2], o[3]);
}

template <bool CROSS>
__device__ __forceinline__ void run(const float* __restrict__ img, float* __restrict__ out,
                                    const bool* m, int gx, int y0, int lx, int H, int W) {
    // prologue: Rows y0-2..y0+1, Eros y0-1, y0
    Raw rb = load_raw(img, y0 - 2, gx, lx, H, W);
    Raw rc = load_raw(img, y0 - 1, gx, lx, H, W);
    Raw rd = load_raw(img, y0,     gx, lx, H, W);
    Raw re = load_raw(img, y0 + 1, gx, lx, H, W);
    Raw pref = load_raw(img, y0 + 2, gx, lx, H, W);   // prefetch for i=0

    Row B   = rowify(rb, lx);
    Row C   = rowify(rc, lx);
    Row Cur = rowify(rd, lx);   // Row(y0)
    Ero E0 = CROSS ? erode_cross(B, C, Cur, y0 - 1, H, gx, W)
                   : erode_gen(B, C, Cur, m, y0 - 1, H, gx, W);
    Row Nxt = rowify(re, lx);   // Row(y0+1)
    Ero E1 = CROSS ? erode_cross(C, Cur, Nxt, y0, H, gx, W)
                   : erode_gen(C, Cur, Nxt, m, y0, H, gx, W);

#pragma unroll
    for (int i = 0; i < RH; ++i) {
        const int y = y0 + i;
        Raw pref2 = pref;
        if (i < RH - 1)                               // compile-time under unroll
            pref2 = load_raw(img, y + 3, gx, lx, H, W);  // prefetch next iter's row
        Row N = rowify(pref, lx);                     // Row(y+2), loaded last iter
        Ero E2 = CROSS ? erode_cross(Cur, Nxt, N, y + 1, H, gx, W)
                       : erode_gen(Cur, Nxt, N, m, y + 1, H, gx, W);
        float4 o = CROSS ? dilate_cross(E0, E1, E2) : dilate_gen(E0, E1, E2, m);
        // NON-TEMPORAL store: keeps the write stream from allocating L2/LLC lines
        // (R5: +5% — the input can't stay LLC-resident anyway, the harness's 402-MB
        // fill between dispatches flushes LLC, but nt still avoids in-flight eviction).
        f32x4 ov; ov.x = o.x; ov.y = o.y; ov.z = o.z; ov.w = o.w;
        __builtin_nontemporal_store(ov, (f32x4*)(out + (size_t)y * W + gx));
        Cur = Nxt; Nxt = N;
        E0 = E1; E1 = E2;
        pref = pref2;
    }
}

// Persistent balanced grid: 1536 blocks = exactly 6 blocks/CU (24 waves/CU resident),
// each grid-striding over strips. 3072 strips / 1536 blocks = exactly 2 strips each:
// zero tail, zero second dispatch round, uniform per-CU work.
__global__ __launch_bounds__(256) void opening_kernel(
    const float* __restrict__ img, const int* __restrict__ kern,
    float* __restrict__ out, int H, int W, int nstrip)
{
    const int lx = threadIdx.x & 63;          // lane -> x strip
    const int ty = threadIdx.x >> 6;          // wave -> y group (wave-uniform)
    const int nx = W >> 8;                    // 256-px strips per row (4)
    const int ny = H / (TY * RH);             // 32-row strip groups (32)

    bool m[9];
#pragma unroll
    for (int k = 0; k < 9; ++k) m[k] = (kern[k] == 1);

    const bool cross = m[1] && m[3] && m[4] && m[5] && m[7] &&
                       !m[0] && !m[2] && !m[6] && !m[8];

    for (int sid = blockIdx.x; sid < nstrip; sid += gridDim.x) {
        const int sx = sid % nx;
        const int sy = (sid / nx) % ny;
        const int sz = sid / (nx * ny);
        const int gx = sx * 256 + lx * 4;
        const int y0 = (sy * TY + ty) * RH;
        const size_t pbase = (size_t)sz * H * W;
        if (cross) run<true >(img + pbase, out + pbase, m, gx, y0, lx, H, W);
        else       run<false>(img + pbase, out + pbase, m, gx, y0, lx, H, W);
    }
}

extern "C" void kernel_launch(void* const* d_in, const int* in_sizes, int n_in,
                              void* d_out, int out_size, void* d_ws, size_t ws_size,
                              hipStream_t stream) {
    const float* img  = (const float*)d_in[0];
    const int*   kern = (const int*)d_in[1];
    float*       out  = (float*)d_out;

    const int H = 1024, W = 1024;
    const int planes = in_sizes[0] / (H * W);      // B*C = 24
    const int nstrip = (W / 256) * (H / (TY * RH)) * planes;   // 4*32*24 = 3072

    dim3 block(256);
    dim3 grid(1536);                               // 6 blocks/CU exact; 2 strips/block
    opening_kernel<<<grid, block, 0, stream>>>(img, kern, out, H, W, nstrip);
}